// Round 11
// baseline (601.761 us; speedup 1.0000x reference)
//
#include <hip/hip_runtime.h>
#include <hip/hip_bf16.h>

#define NN 65536
#define DD 512
#define HH 512
#define NSTEP 4
#define NEG_INFF -100000000.0f

#define RPW 8                  // rows per wave in attn_partial
#define ABLOCKS 2048
#define NWAVE (ABLOCKS * 4)    // 8192 waves x 8 rows = 65536

typedef unsigned short ushort_t;
typedef __attribute__((ext_vector_type(8))) short bf16x8;
typedef __attribute__((ext_vector_type(4))) float f32x4;

// ---------- helpers ----------
__device__ __forceinline__ float bflo(unsigned u) {
    union { unsigned i; float f; } v; v.i = u << 16; return v.f;
}
__device__ __forceinline__ float bfhi(unsigned u) {
    union { unsigned i; float f; } v; v.i = u & 0xffff0000u; return v.f;
}
__device__ __forceinline__ float fast_tanh(float x) {
    float e = __expf(2.0f * x);
    return 1.0f - 2.0f * __builtin_amdgcn_rcpf(e + 1.0f);
}

#define GL2LDS(g, l) __builtin_amdgcn_global_load_lds( \
    (const __attribute__((address_space(1))) unsigned int*)(g), \
    (__attribute__((address_space(3))) unsigned int*)(l), 16, 0, 0)

// ---------- f32 -> bf16 convert (attn_mem) ----------
__global__ __launch_bounds__(256)
void conv_bf16(const float* __restrict__ in, ushort_t* __restrict__ out) {
    const int i = blockIdx.x * 256 + threadIdx.x;
    const size_t base = (size_t)i * 8;
    float4 a = *(const float4*)&in[base];
    float4 b = *(const float4*)&in[base + 4];
    union { __hip_bfloat16 h[8]; uint4 u; } t;
    t.h[0] = __float2bfloat16(a.x); t.h[1] = __float2bfloat16(a.y);
    t.h[2] = __float2bfloat16(a.z); t.h[3] = __float2bfloat16(a.w);
    t.h[4] = __float2bfloat16(b.x); t.h[5] = __float2bfloat16(b.y);
    t.h[6] = __float2bfloat16(b.z); t.h[7] = __float2bfloat16(b.w);
    *(uint4*)&out[base] = t.u;
}

// ---------- weight transpose + convert: WT[n][k] = bf16(W[k][n]) ----------
__global__ __launch_bounds__(256)
void conv_wt(const float* __restrict__ W0, const float* __restrict__ W1,
             ushort_t* __restrict__ T0, ushort_t* __restrict__ T1) {
    const float* W = blockIdx.y ? W1 : W0;
    ushort_t* T = blockIdx.y ? T1 : T0;
    const int n = blockIdx.x * 4 + (threadIdx.x >> 6);
    const int k0 = (threadIdx.x & 63) * 8;
    union { __hip_bfloat16 h[8]; uint4 u; } t;
#pragma unroll
    for (int i = 0; i < 8; ++i)
        t.h[i] = __float2bfloat16(W[(size_t)(k0 + i) * HH + n]);
    *(uint4*)&T[(size_t)n * DD + k0] = t.u;
}

// ---------- MFMA GEMM: XCD-locality grid + 2-phase LDS double-buffer ----------
#define TM 128
#define TK 32
#define NT (DD / TK)   // 16 K-steps
__global__ __launch_bounds__(256)
void gemm_mfma(const ushort_t* __restrict__ A,
               const ushort_t* __restrict__ WT0, const ushort_t* __restrict__ WT1,
               __hip_bfloat16* __restrict__ C0, __hip_bfloat16* __restrict__ C1) {
    __shared__ ushort_t As[2][TM * TK];
    __shared__ ushort_t Bs[2][TM * TK];
    const int L = blockIdx.x;
    const int xcd = L & 7;
    const int slot = L >> 3;
    const int mt = xcd * 64 + (slot >> 3);
    const int my = slot & 7;
    const ushort_t* WT = (my < 4) ? WT0 : WT1;
    __hip_bfloat16* Cp = (my < 4) ? C0 : C1;
    const int bn = (my & 3) * TM;
    const int bm = mt * TM;
    const int tid = threadIdx.x;
    const int lane = tid & 63;
    const int wid = tid >> 6;
    const int wr = (wid >> 1) * 64;
    const int wc = (wid & 1) * 64;
    const int l15 = lane & 15;
    const int srow = lane >> 2;
    const int ske = (((lane & 3) ^ ((lane >> 3) & 3)) * 8);
    const int koff = (((lane >> 4) ^ ((l15 >> 1) & 3)) << 3);

    const ushort_t* Abase = A + (size_t)bm * DD;
    const ushort_t* Bbase = WT + (size_t)bn * DD;

    auto stage = [&](int b, int k0) {
#pragma unroll
        for (int u = 0; u < 2; ++u) {
            const int g = u * 4 + wid;
            const int row = g * 16 + srow;
            GL2LDS(Abase + (size_t)row * DD + k0 + ske, &As[b][g * 512]);
            GL2LDS(Bbase + (size_t)row * DD + k0 + ske, &Bs[b][g * 512]);
        }
    };

    const f32x4 zero = {0.f, 0.f, 0.f, 0.f};
    f32x4 acc[4][4];
#pragma unroll
    for (int m = 0; m < 4; ++m)
#pragma unroll
        for (int n = 0; n < 4; ++n) acc[m][n] = zero;

    stage(0, 0);
    stage(1, TK);
    __builtin_amdgcn_sched_barrier(0);

    for (int t = 0; t < NT; ++t) {
        const int cur = t & 1;
        if (t + 1 < NT) asm volatile("s_waitcnt vmcnt(4)" ::: "memory");
        else            asm volatile("s_waitcnt vmcnt(0)" ::: "memory");
        __builtin_amdgcn_sched_barrier(0);
        __builtin_amdgcn_s_barrier();
        __builtin_amdgcn_sched_barrier(0);

        bf16x8 af[4], bfr[4];
#pragma unroll
        for (int m = 0; m < 4; ++m)
            af[m] = *(const bf16x8*)(&As[cur][(wr + m * 16 + l15) * TK + koff]);
#pragma unroll
        for (int n = 0; n < 4; ++n)
            bfr[n] = *(const bf16x8*)(&Bs[cur][(wc + n * 16 + l15) * TK + koff]);
#pragma unroll
        for (int m = 0; m < 4; ++m)
#pragma unroll
            for (int n = 0; n < 4; ++n)
                acc[m][n] = __builtin_amdgcn_mfma_f32_16x16x32_bf16(af[m], bfr[n], acc[m][n], 0, 0, 0);

        asm volatile("s_waitcnt lgkmcnt(0)" ::: "memory");
        __builtin_amdgcn_sched_barrier(0);
        __builtin_amdgcn_s_barrier();
        __builtin_amdgcn_sched_barrier(0);
        if (t + 2 < NT) stage(cur, (t + 2) * TK);
        __builtin_amdgcn_sched_barrier(0);
    }

    const int r0 = (lane >> 4) * 4;
#pragma unroll
    for (int m = 0; m < 4; ++m) {
#pragma unroll
        for (int n = 0; n < 4; ++n) {
            const f32x4 vv = acc[m][n];
            const size_t cb = (size_t)(bm + wr + m * 16 + r0) * HH + bn + wc + n * 16 + l15;
#pragma unroll
            for (int r = 0; r < 4; ++r)
                Cp[cb + (size_t)r * HH] = __float2bfloat16(vv[r]);
        }
    }
}

// ---------- LSTM gates ----------
__global__ __launch_bounds__(256)
void lstm_gates(const float* __restrict__ x, const float* __restrict__ h,
                const float* __restrict__ w_ih, const float* __restrict__ w_hh,
                const float* __restrict__ b_ih, const float* __restrict__ b_hh,
                float* __restrict__ gates) {
    const int wave = (blockIdx.x * 256 + threadIdx.x) >> 6;
    const int lane = threadIdx.x & 63;
    const float* wi = w_ih + (size_t)wave * DD;
    const float* wh = w_hh + (size_t)wave * HH;
    float s = 0.f;
#pragma unroll
    for (int t = 0; t < 8; ++t) {
        int k = lane + 64 * t;
        s += wi[k] * x[k] + wh[k] * h[k];
    }
#pragma unroll
    for (int off = 32; off; off >>= 1) s += __shfl_xor(s, off, 64);
    if (lane == 0) gates[wave] = s + b_ih[wave] + b_hh[wave];
}

// ---------- fused LSTM h/c + qw = h @ hop_wq ----------
__global__ __launch_bounds__(512)
void lstm_tail(const float* __restrict__ gates, const float* __restrict__ cin,
               float* __restrict__ cout, float* __restrict__ hout,
               const float* __restrict__ Wq, float* __restrict__ qwout) {
    __shared__ float hs[HH];
    __shared__ float red[8][64];
    const int j = threadIdx.x;
    {
        float ig = gates[j], fg = gates[HH + j], gg = gates[2 * HH + j], og = gates[3 * HH + j];
        float si = 1.f / (1.f + __expf(-ig));
        float sf = 1.f / (1.f + __expf(-fg));
        float so = 1.f / (1.f + __expf(-og));
        float cn = sf * cin[j] + si * tanhf(gg);
        float hn = so * tanhf(cn);
        hs[j] = hn;
        if (blockIdx.x == 0) { cout[j] = cn; hout[j] = hn; }
    }
    __syncthreads();
    const int lane = threadIdx.x & 63, wv = threadIdx.x >> 6;
    const int col = blockIdx.x * 64 + lane;
    float s = 0.f;
    const int k0 = wv * 64;
#pragma unroll 4
    for (int k = k0; k < k0 + 64; ++k) s += hs[k] * Wq[(size_t)k * HH + col];
    red[wv][lane] = s;
    __syncthreads();
    if (wv == 0) {
        float t = 0.f;
#pragma unroll
        for (int r = 0; r < 8; ++r) t += red[r][lane];
        qwout[col] = t;
    }
}

// ---------- qw = q @ W (512x512), grid 8 x 512 ----------
__global__ __launch_bounds__(512)
void vecmat512(const float* __restrict__ q, const float* __restrict__ W,
               float* __restrict__ out) {
    __shared__ float red[8][64];
    const int lane = threadIdx.x & 63, wv = threadIdx.x >> 6;
    const int j = blockIdx.x * 64 + lane;
    float s = 0.f;
    const int k0 = wv * 64;
#pragma unroll 4
    for (int k = k0; k < k0 + 64; ++k) s += q[k] * W[(size_t)k * HH + j];
    red[wv][lane] = s;
    __syncthreads();
    if (wv == 0) {
        float t = 0.f;
#pragma unroll
        for (int r = 0; r < 8; ++r) t += red[r][lane];
        out[j] = t;
    }
}

// ---------- attention phase A: fixed-offset exp partials (r6 2-deep body) ----------
// softmax(sc) = exp(sc-C)/sum exp(sc-C) with C = sum|v| >= max sc (tanh in [-1,1])
template<bool HOP>
__global__ __launch_bounds__(256)
void attn_partial(const ushort_t* __restrict__ feat,
                  const ushort_t* __restrict__ mem,
                  const float* __restrict__ qw,
                  const float* __restrict__ v,
                  const int* __restrict__ mask,
                  float* __restrict__ pl, float* __restrict__ pacc) {
    const int gtid = blockIdx.x * 256 + threadIdx.x;
    const int wave = gtid >> 6;
    const int lane = threadIdx.x & 63;
    float qv[8], vv[8];
    {
        float4 q0 = *(const float4*)&qw[lane * 8];
        float4 q1 = *(const float4*)&qw[lane * 8 + 4];
        qv[0] = q0.x; qv[1] = q0.y; qv[2] = q0.z; qv[3] = q0.w;
        qv[4] = q1.x; qv[5] = q1.y; qv[6] = q1.z; qv[7] = q1.w;
        float4 v0 = *(const float4*)&v[lane * 8];
        float4 v1 = *(const float4*)&v[lane * 8 + 4];
        vv[0] = v0.x; vv[1] = v0.y; vv[2] = v0.z; vv[3] = v0.w;
        vv[4] = v1.x; vv[5] = v1.y; vv[6] = v1.z; vv[7] = v1.w;
    }
    float C = 0.f;
#pragma unroll
    for (int j = 0; j < 8; ++j) C += fabsf(vv[j]);
#pragma unroll
    for (int off = 32; off; off >>= 1) C += __shfl_xor(C, off, 64);

    float lsum = 0.f;
    float acc[8];
#pragma unroll
    for (int j = 0; j < 8; ++j) acc[j] = 0.f;
    const int row0 = wave * RPW;

    uint4 fc = *(const uint4*)(feat + (size_t)row0 * HH + lane * 8);
    uint4 mc;
    if (!HOP) mc = *(const uint4*)(mem + (size_t)row0 * DD + lane * 8);
#pragma unroll 4
    for (int r = 0; r < RPW; ++r) {
        uint4 fn, mn;
        if (r + 1 < RPW) {
            fn = *(const uint4*)(feat + (size_t)(row0 + r + 1) * HH + lane * 8);
            if (!HOP) mn = *(const uint4*)(mem + (size_t)(row0 + r + 1) * DD + lane * 8);
        }
        float f[8];
        f[0] = bflo(fc.x); f[1] = bfhi(fc.x); f[2] = bflo(fc.y); f[3] = bfhi(fc.y);
        f[4] = bflo(fc.z); f[5] = bfhi(fc.z); f[6] = bflo(fc.w); f[7] = bfhi(fc.w);
        float mv[8];
        if (!HOP) {
            mv[0] = bflo(mc.x); mv[1] = bfhi(mc.x); mv[2] = bflo(mc.y); mv[3] = bfhi(mc.y);
            mv[4] = bflo(mc.z); mv[5] = bfhi(mc.z); mv[6] = bflo(mc.w); mv[7] = bfhi(mc.w);
        } else {
#pragma unroll
            for (int j = 0; j < 8; ++j) mv[j] = f[j];
        }
        float d = 0.f;
#pragma unroll
        for (int j = 0; j < 8; ++j) d += fast_tanh(f[j] + qv[j]) * vv[j];
#pragma unroll
        for (int off = 32; off; off >>= 1) d += __shfl_xor(d, off, 64);
        const float sc = d - C + (mask[row0 + r] ? 0.f : NEG_INFF);
        const float p = __expf(sc);
        lsum += p;
#pragma unroll
        for (int j = 0; j < 8; ++j) acc[j] += p * mv[j];
        fc = fn;
        if (!HOP) mc = mn;
    }
    const size_t base = (size_t)wave * HH + lane * 8;
    *(float4*)&pacc[base]     = make_float4(acc[0], acc[1], acc[2], acc[3]);
    *(float4*)&pacc[base + 4] = make_float4(acc[4], acc[5], acc[6], acc[7]);
    if (lane == 0) pl[wave] = lsum;
}

// ---------- attention phase B: plain sum of partials; grid 64 x 256 ----------
__global__ __launch_bounds__(256)
void attn_combine(const float* __restrict__ pl, const float* __restrict__ pacc,
                  float* __restrict__ out) {
    __shared__ float red[256];
    const int tid = threadIdx.x;
    const int lane = tid & 63, wv = tid >> 6;
    float lg = 0.f;
    for (int b = tid; b < NWAVE; b += 256) lg += pl[b];
#pragma unroll
    for (int off = 32; off; off >>= 1) lg += __shfl_xor(lg, off, 64);
    if (lane == 0) red[wv] = lg;
    __syncthreads();
    lg = red[0] + red[1] + red[2] + red[3];
    const float inv = 1.0f / lg;
    __syncthreads();
    const int c0 = blockIdx.x * 8;
    float a[8];
#pragma unroll
    for (int j = 0; j < 8; ++j) a[j] = 0.f;
    for (int b = tid; b < NWAVE; b += 256) {
        float4 p0 = *(const float4*)&pacc[(size_t)b * HH + c0];
        float4 p1 = *(const float4*)&pacc[(size_t)b * HH + c0 + 4];
        a[0] += p0.x; a[1] += p0.y; a[2] += p0.z; a[3] += p0.w;
        a[4] += p1.x; a[5] += p1.y; a[6] += p1.z; a[7] += p1.w;
    }
#pragma unroll
    for (int j = 0; j < 8; ++j)
#pragma unroll
        for (int off = 32; off; off >>= 1) a[j] += __shfl_xor(a[j], off, 64);
    if (lane == 0) {
#pragma unroll
        for (int j = 0; j < 8; ++j) red[wv * 8 + j] = a[j];
    }
    __syncthreads();
    if (tid < 8) {
        float s = red[tid] + red[8 + tid] + red[16 + tid] + red[24 + tid];
        out[c0 + tid] = s * inv;
    }
}

// ---------- score ----------
__global__ void score_k(const float* __restrict__ x, const float* __restrict__ sw,
                        const float* __restrict__ sb, float* __restrict__ out) {
    const int lane = threadIdx.x;   // 64
    float s = 0.f;
#pragma unroll
    for (int t = 0; t < 8; ++t) {
        int k = lane + 64 * t;
        s += x[k] * sw[k];
    }
#pragma unroll
    for (int off = 32; off; off >>= 1) s += __shfl_xor(s, off, 64);
    if (lane == 0) out[0] = s + sb[0];
}

// ---------- launcher ----------
extern "C" void kernel_launch(void* const* d_in, const int* in_sizes, int n_in,
                              void* d_out, int out_size, void* d_ws, size_t ws_size,
                              hipStream_t stream) {
    (void)in_sizes; (void)n_in; (void)out_size; (void)ws_size;
    const float* attn_mem = (const float*)d_in[0];
    const float* attn_wm  = (const float*)d_in[1];
    const float* attn_wq  = (const float*)d_in[2];
    const float* attn_v   = (const float*)d_in[3];
    const float* hop_wm   = (const float*)d_in[4];
    const float* hop_wq   = (const float*)d_in[5];
    const float* hop_v    = (const float*)d_in[6];
    const float* init_i   = (const float*)d_in[7];
    const float* init_h   = (const float*)d_in[8];
    const float* init_c   = (const float*)d_in[9];
    const float* w_ih     = (const float*)d_in[10];
    const float* w_hh     = (const float*)d_in[11];
    const float* b_ih     = (const float*)d_in[12];
    const float* b_hh     = (const float*)d_in[13];
    const float* score_w  = (const float*)d_in[14];
    const float* score_b  = (const float*)d_in[15];
    const int*   mask     = (const int*)d_in[16];
    float* dout = (float*)d_out;

    size_t off = 0;
    char* base = (char*)d_ws;
    auto carve = [&](size_t bytes) -> char* {
        char* p = base + off;
        off += (bytes + 255) & ~(size_t)255;
        return p;
    };
    ushort_t* Abf  = (ushort_t*)carve((size_t)NN * DD * 2);
    ushort_t* WT0  = (ushort_t*)carve((size_t)DD * HH * 2);
    ushort_t* WT1  = (ushort_t*)carve((size_t)DD * HH * 2);
    ushort_t* afeat = (ushort_t*)carve((size_t)NN * HH * 2);
    ushort_t* hfeat = (ushort_t*)carve((size_t)NN * HH * 2);
    float* pacc  = (float*)carve((size_t)NWAVE * HH * 4);
    float* pl    = (float*)carve((size_t)NWAVE * 4);
    float* gates = (float*)carve(4 * HH * 4);
    float* hbuf  = (float*)carve(HH * 4);
    float* cb0   = (float*)carve(HH * 4);
    float* cb1   = (float*)carve(HH * 4);
    float* qbuf  = (float*)carve(HH * 4);
    float* qwbuf = (float*)carve(HH * 4);
    float* xbuf  = (float*)carve(DD * 4);

    conv_bf16<<<(NN * DD / 8) / 256, 256, 0, stream>>>(attn_mem, Abf);
    conv_wt<<<dim3(128, 2), 256, 0, stream>>>(attn_wm, hop_wm, WT0, WT1);
    gemm_mfma<<<4096, 256, 0, stream>>>(Abf, WT0, WT1,
        (__hip_bfloat16*)afeat, (__hip_bfloat16*)hfeat);

    for (int s = 0; s < NSTEP; ++s) {
        const float* x   = s ? xbuf : init_i;
        const float* hin = s ? hbuf : init_h;
        const float* cin = s == 0 ? init_c : (s & 1 ? cb0 : cb1);
        float* cout      = (s & 1) ? cb1 : cb0;
        lstm_gates<<<512, 256, 0, stream>>>(x, hin, w_ih, w_hh, b_ih, b_hh, gates);
        lstm_tail<<<8, 512, 0, stream>>>(gates, cin, cout, hbuf, hop_wq, qwbuf);
        attn_partial<true><<<ABLOCKS, 256, 0, stream>>>(hfeat, nullptr, qwbuf, hop_v, mask, pl, pacc);
        attn_combine<<<64, 256, 0, stream>>>(pl, pacc, qbuf);
        vecmat512<<<8, 512, 0, stream>>>(qbuf, attn_wq, qwbuf);
        attn_partial<false><<<ABLOCKS, 256, 0, stream>>>(afeat, Abf, qwbuf, attn_v, mask, pl, pacc);
        attn_combine<<<64, 256, 0, stream>>>(pl, pacc, xbuf);
        score_k<<<1, 64, 0, stream>>>(xbuf, score_w, score_b, dout + s);
    }
}

// Round 12
// 501.708 us; speedup vs baseline: 1.1994x; 1.1994x over previous
//
#include <hip/hip_runtime.h>
#include <hip/hip_bf16.h>

#define NN 65536
#define DD 512
#define HH 512
#define NSTEP 4
#define NEG_INFF -100000000.0f

#define RPW 16                 // rows per wave in attn_partial (r6-proven)
#define ABLOCKS 1024
#define NWAVE (ABLOCKS * 4)    // 4096 waves x 16 rows = 65536

typedef unsigned short ushort_t;
typedef __attribute__((ext_vector_type(8))) short bf16x8;
typedef __attribute__((ext_vector_type(4))) float f32x4;

// ---------- helpers ----------
__device__ __forceinline__ float bflo(unsigned u) {
    union { unsigned i; float f; } v; v.i = u << 16; return v.f;
}
__device__ __forceinline__ float bfhi(unsigned u) {
    union { unsigned i; float f; } v; v.i = u & 0xffff0000u; return v.f;
}
__device__ __forceinline__ float fast_tanh(float x) {
    float e = __expf(2.0f * x);
    return 1.0f - 2.0f * __builtin_amdgcn_rcpf(e + 1.0f);
}

#define GL2LDS(g, l) __builtin_amdgcn_global_load_lds( \
    (const __attribute__((address_space(1))) unsigned int*)(g), \
    (__attribute__((address_space(3))) unsigned int*)(l), 16, 0, 0)

// ---------- f32 -> bf16 convert (attn_mem) ----------
__global__ __launch_bounds__(256)
void conv_bf16(const float* __restrict__ in, ushort_t* __restrict__ out) {
    const int i = blockIdx.x * 256 + threadIdx.x;
    const size_t base = (size_t)i * 8;
    float4 a = *(const float4*)&in[base];
    float4 b = *(const float4*)&in[base + 4];
    union { __hip_bfloat16 h[8]; uint4 u; } t;
    t.h[0] = __float2bfloat16(a.x); t.h[1] = __float2bfloat16(a.y);
    t.h[2] = __float2bfloat16(a.z); t.h[3] = __float2bfloat16(a.w);
    t.h[4] = __float2bfloat16(b.x); t.h[5] = __float2bfloat16(b.y);
    t.h[6] = __float2bfloat16(b.z); t.h[7] = __float2bfloat16(b.w);
    *(uint4*)&out[base] = t.u;
}

// ---------- weight transpose + convert: WT[n][k] = bf16(W[k][n]) ----------
__global__ __launch_bounds__(256)
void conv_wt(const float* __restrict__ W0, const float* __restrict__ W1,
             ushort_t* __restrict__ T0, ushort_t* __restrict__ T1) {
    const float* W = blockIdx.y ? W1 : W0;
    ushort_t* T = blockIdx.y ? T1 : T0;
    const int n = blockIdx.x * 4 + (threadIdx.x >> 6);
    const int k0 = (threadIdx.x & 63) * 8;
    union { __hip_bfloat16 h[8]; uint4 u; } t;
#pragma unroll
    for (int i = 0; i < 8; ++i)
        t.h[i] = __float2bfloat16(W[(size_t)(k0 + i) * HH + n]);
    *(uint4*)&T[(size_t)n * DD + k0] = t.u;
}

// ---------- MFMA GEMM: XCD grid + 2-phase dbuf + LDS-transposed epilogue ----------
#define TM 128
#define TK 32
#define NT (DD / TK)   // 16 K-steps
__global__ __launch_bounds__(256)
void gemm_mfma(const ushort_t* __restrict__ A,
               const ushort_t* __restrict__ WT0, const ushort_t* __restrict__ WT1,
               __hip_bfloat16* __restrict__ C0, __hip_bfloat16* __restrict__ C1) {
    __shared__ char smem[32768];
    ushort_t* AsB = (ushort_t*)smem;            // [2][4096] ushorts
    ushort_t* BsB = (ushort_t*)(smem + 16384);  // [2][4096] ushorts
    const int L = blockIdx.x;
    const int xcd = L & 7;
    const int slot = L >> 3;
    const int mt = xcd * 64 + (slot >> 3);
    const int my = slot & 7;
    const ushort_t* WT = (my < 4) ? WT0 : WT1;
    __hip_bfloat16* Cp = (my < 4) ? C0 : C1;
    const int bn = (my & 3) * TM;
    const int bm = mt * TM;
    const int tid = threadIdx.x;
    const int lane = tid & 63;
    const int wid = tid >> 6;
    const int wr = (wid >> 1) * 64;
    const int wc = (wid & 1) * 64;
    const int l15 = lane & 15;
    const int srow = lane >> 2;
    const int ske = (((lane & 3) ^ ((lane >> 3) & 3)) * 8);
    const int koff = (((lane >> 4) ^ ((l15 >> 1) & 3)) << 3);

    const ushort_t* Abase = A + (size_t)bm * DD;
    const ushort_t* Bbase = WT + (size_t)bn * DD;

    auto stage = [&](int b, int k0) {
#pragma unroll
        for (int u = 0; u < 2; ++u) {
            const int g = u * 4 + wid;
            const int row = g * 16 + srow;
            GL2LDS(Abase + (size_t)row * DD + k0 + ske, AsB + b * 4096 + g * 512);
            GL2LDS(Bbase + (size_t)row * DD + k0 + ske, BsB + b * 4096 + g * 512);
        }
    };

    const f32x4 zero = {0.f, 0.f, 0.f, 0.f};
    f32x4 acc[4][4];
#pragma unroll
    for (int m = 0; m < 4; ++m)
#pragma unroll
        for (int n = 0; n < 4; ++n) acc[m][n] = zero;

    stage(0, 0);
    stage(1, TK);
    __builtin_amdgcn_sched_barrier(0);

    for (int t = 0; t < NT; ++t) {
        const int cur = t & 1;
        if (t + 1 < NT) asm volatile("s_waitcnt vmcnt(4)" ::: "memory");
        else            asm volatile("s_waitcnt vmcnt(0)" ::: "memory");
        __builtin_amdgcn_sched_barrier(0);
        __builtin_amdgcn_s_barrier();
        __builtin_amdgcn_sched_barrier(0);

        bf16x8 af[4], bfr[4];
#pragma unroll
        for (int m = 0; m < 4; ++m)
            af[m] = *(const bf16x8*)(AsB + cur * 4096 + (wr + m * 16 + l15) * TK + koff);
#pragma unroll
        for (int n = 0; n < 4; ++n)
            bfr[n] = *(const bf16x8*)(BsB + cur * 4096 + (wc + n * 16 + l15) * TK + koff);
#pragma unroll
        for (int m = 0; m < 4; ++m)
#pragma unroll
            for (int n = 0; n < 4; ++n)
                acc[m][n] = __builtin_amdgcn_mfma_f32_16x16x32_bf16(af[m], bfr[n], acc[m][n], 0, 0, 0);

        asm volatile("s_waitcnt lgkmcnt(0)" ::: "memory");
        __builtin_amdgcn_sched_barrier(0);
        __builtin_amdgcn_s_barrier();
        __builtin_amdgcn_sched_barrier(0);
        if (t + 2 < NT) stage(cur, (t + 2) * TK);
        __builtin_amdgcn_sched_barrier(0);
    }

    // Epilogue: per-wave LDS transpose (reuse dead As/Bs), then 16B stores.
    // Cs region per wave: 16 rows x 68 floats (pad 68: 16B-aligned rows, banks spread)
    float* Cs = (float*)smem + wid * (16 * 68);
    const int r0w = (lane >> 4) * 4;
    const int lr = lane >> 2;          // 0..15
    const int lc = (lane & 3) * 16;    // 0,16,32,48
#pragma unroll
    for (int m = 0; m < 4; ++m) {
#pragma unroll
        for (int n = 0; n < 4; ++n) {
            const f32x4 vvv = acc[m][n];
#pragma unroll
            for (int r = 0; r < 4; ++r)
                Cs[(r0w + r) * 68 + n * 16 + l15] = vvv[r];
        }
        asm volatile("s_waitcnt lgkmcnt(0)" ::: "memory");
        __builtin_amdgcn_s_barrier();
        union { __hip_bfloat16 h[16]; uint4 u[2]; } pk;
#pragma unroll
        for (int j = 0; j < 16; ++j)
            pk.h[j] = __float2bfloat16(Cs[lr * 68 + lc + j]);
        const size_t rb = (size_t)(bm + wr + m * 16 + lr) * HH + bn + wc + lc;
        *(uint4*)&Cp[rb]     = pk.u[0];
        *(uint4*)&Cp[rb + 8] = pk.u[1];
        asm volatile("s_waitcnt lgkmcnt(0)" ::: "memory");
        __builtin_amdgcn_s_barrier();
    }
}

// ---------- LSTM gates ----------
__global__ __launch_bounds__(256)
void lstm_gates(const float* __restrict__ x, const float* __restrict__ h,
                const float* __restrict__ w_ih, const float* __restrict__ w_hh,
                const float* __restrict__ b_ih, const float* __restrict__ b_hh,
                float* __restrict__ gates) {
    const int wave = (blockIdx.x * 256 + threadIdx.x) >> 6;
    const int lane = threadIdx.x & 63;
    const float* wi = w_ih + (size_t)wave * DD;
    const float* wh = w_hh + (size_t)wave * HH;
    float s = 0.f;
#pragma unroll
    for (int t = 0; t < 8; ++t) {
        int k = lane + 64 * t;
        s += wi[k] * x[k] + wh[k] * h[k];
    }
#pragma unroll
    for (int off = 32; off; off >>= 1) s += __shfl_xor(s, off, 64);
    if (lane == 0) gates[wave] = s + b_ih[wave] + b_hh[wave];
}

// ---------- fused LSTM h/c + qw = h @ hop_wq ----------
__global__ __launch_bounds__(512)
void lstm_tail(const float* __restrict__ gates, const float* __restrict__ cin,
               float* __restrict__ cout, float* __restrict__ hout,
               const float* __restrict__ Wq, float* __restrict__ qwout) {
    __shared__ float hs[HH];
    __shared__ float red[8][64];
    const int j = threadIdx.x;
    {
        float ig = gates[j], fg = gates[HH + j], gg = gates[2 * HH + j], og = gates[3 * HH + j];
        float si = 1.f / (1.f + __expf(-ig));
        float sf = 1.f / (1.f + __expf(-fg));
        float so = 1.f / (1.f + __expf(-og));
        float cn = sf * cin[j] + si * tanhf(gg);
        float hn = so * tanhf(cn);
        hs[j] = hn;
        if (blockIdx.x == 0) { cout[j] = cn; hout[j] = hn; }
    }
    __syncthreads();
    const int lane = threadIdx.x & 63, wv = threadIdx.x >> 6;
    const int col = blockIdx.x * 64 + lane;
    float s = 0.f;
    const int k0 = wv * 64;
#pragma unroll 4
    for (int k = k0; k < k0 + 64; ++k) s += hs[k] * Wq[(size_t)k * HH + col];
    red[wv][lane] = s;
    __syncthreads();
    if (wv == 0) {
        float t = 0.f;
#pragma unroll
        for (int r = 0; r < 8; ++r) t += red[r][lane];
        qwout[col] = t;
    }
}

// ---------- qw = q @ W (512x512), grid 8 x 512 ----------
__global__ __launch_bounds__(512)
void vecmat512(const float* __restrict__ q, const float* __restrict__ W,
               float* __restrict__ out) {
    __shared__ float red[8][64];
    const int lane = threadIdx.x & 63, wv = threadIdx.x >> 6;
    const int j = blockIdx.x * 64 + lane;
    float s = 0.f;
    const int k0 = wv * 64;
#pragma unroll 4
    for (int k = k0; k < k0 + 64; ++k) s += q[k] * W[(size_t)k * HH + j];
    red[wv][lane] = s;
    __syncthreads();
    if (wv == 0) {
        float t = 0.f;
#pragma unroll
        for (int r = 0; r < 8; ++r) t += red[r][lane];
        out[j] = t;
    }
}

// ---------- attention phase A: fixed-offset exp partials (r6-proven body) ----------
template<bool HOP>
__global__ __launch_bounds__(256)
void attn_partial(const ushort_t* __restrict__ feat,
                  const ushort_t* __restrict__ mem,
                  const float* __restrict__ qw,
                  const float* __restrict__ v,
                  const int* __restrict__ mask,
                  float* __restrict__ pl, float* __restrict__ pacc) {
    const int gtid = blockIdx.x * 256 + threadIdx.x;
    const int wave = gtid >> 6;
    const int lane = threadIdx.x & 63;
    float qv[8], vv[8];
    {
        float4 q0 = *(const float4*)&qw[lane * 8];
        float4 q1 = *(const float4*)&qw[lane * 8 + 4];
        qv[0] = q0.x; qv[1] = q0.y; qv[2] = q0.z; qv[3] = q0.w;
        qv[4] = q1.x; qv[5] = q1.y; qv[6] = q1.z; qv[7] = q1.w;
        float4 v0 = *(const float4*)&v[lane * 8];
        float4 v1 = *(const float4*)&v[lane * 8 + 4];
        vv[0] = v0.x; vv[1] = v0.y; vv[2] = v0.z; vv[3] = v0.w;
        vv[4] = v1.x; vv[5] = v1.y; vv[6] = v1.z; vv[7] = v1.w;
    }
    float C = 0.f;
#pragma unroll
    for (int j = 0; j < 8; ++j) C += fabsf(vv[j]);
#pragma unroll
    for (int off = 32; off; off >>= 1) C += __shfl_xor(C, off, 64);

    float lsum = 0.f;
    float acc[8];
#pragma unroll
    for (int j = 0; j < 8; ++j) acc[j] = 0.f;
    const int row0 = wave * RPW;

    uint4 fc = *(const uint4*)(feat + (size_t)row0 * HH + lane * 8);
    uint4 mc;
    if (!HOP) mc = *(const uint4*)(mem + (size_t)row0 * DD + lane * 8);
#pragma unroll 4
    for (int r = 0; r < RPW; ++r) {
        uint4 fn, mn;
        if (r + 1 < RPW) {
            fn = *(const uint4*)(feat + (size_t)(row0 + r + 1) * HH + lane * 8);
            if (!HOP) mn = *(const uint4*)(mem + (size_t)(row0 + r + 1) * DD + lane * 8);
        }
        float f[8];
        f[0] = bflo(fc.x); f[1] = bfhi(fc.x); f[2] = bflo(fc.y); f[3] = bfhi(fc.y);
        f[4] = bflo(fc.z); f[5] = bfhi(fc.z); f[6] = bflo(fc.w); f[7] = bfhi(fc.w);
        float mv[8];
        if (!HOP) {
            mv[0] = bflo(mc.x); mv[1] = bfhi(mc.x); mv[2] = bflo(mc.y); mv[3] = bfhi(mc.y);
            mv[4] = bflo(mc.z); mv[5] = bfhi(mc.z); mv[6] = bflo(mc.w); mv[7] = bfhi(mc.w);
        } else {
#pragma unroll
            for (int j = 0; j < 8; ++j) mv[j] = f[j];
        }
        float d = 0.f;
#pragma unroll
        for (int j = 0; j < 8; ++j) d += fast_tanh(f[j] + qv[j]) * vv[j];
#pragma unroll
        for (int off = 32; off; off >>= 1) d += __shfl_xor(d, off, 64);
        const float sc = d - C + (mask[row0 + r] ? 0.f : NEG_INFF);
        const float p = __expf(sc);
        lsum += p;
#pragma unroll
        for (int j = 0; j < 8; ++j) acc[j] += p * mv[j];
        fc = fn;
        if (!HOP) mc = mn;
    }
    const size_t base = (size_t)wave * HH + lane * 8;
    *(float4*)&pacc[base]     = make_float4(acc[0], acc[1], acc[2], acc[3]);
    *(float4*)&pacc[base + 4] = make_float4(acc[4], acc[5], acc[6], acc[7]);
    if (lane == 0) pl[wave] = lsum;
}

// ---------- attention phase B: plain sum of partials; grid 64 x 256 ----------
__global__ __launch_bounds__(256)
void attn_combine(const float* __restrict__ pl, const float* __restrict__ pacc,
                  float* __restrict__ out) {
    __shared__ float red[256];
    const int tid = threadIdx.x;
    const int lane = tid & 63, wv = tid >> 6;
    float lg = 0.f;
    for (int b = tid; b < NWAVE; b += 256) lg += pl[b];
#pragma unroll
    for (int off = 32; off; off >>= 1) lg += __shfl_xor(lg, off, 64);
    if (lane == 0) red[wv] = lg;
    __syncthreads();
    lg = red[0] + red[1] + red[2] + red[3];
    const float inv = 1.0f / lg;
    __syncthreads();
    const int c0 = blockIdx.x * 8;
    float a[8];
#pragma unroll
    for (int j = 0; j < 8; ++j) a[j] = 0.f;
    for (int b = tid; b < NWAVE; b += 256) {
        float4 p0 = *(const float4*)&pacc[(size_t)b * HH + c0];
        float4 p1 = *(const float4*)&pacc[(size_t)b * HH + c0 + 4];
        a[0] += p0.x; a[1] += p0.y; a[2] += p0.z; a[3] += p0.w;
        a[4] += p1.x; a[5] += p1.y; a[6] += p1.z; a[7] += p1.w;
    }
#pragma unroll
    for (int j = 0; j < 8; ++j)
#pragma unroll
        for (int off = 32; off; off >>= 1) a[j] += __shfl_xor(a[j], off, 64);
    if (lane == 0) {
#pragma unroll
        for (int j = 0; j < 8; ++j) red[wv * 8 + j] = a[j];
    }
    __syncthreads();
    if (tid < 8) {
        float s = red[tid] + red[8 + tid] + red[16 + tid] + red[24 + tid];
        out[c0 + tid] = s * inv;
    }
}

// ---------- score ----------
__global__ void score_k(const float* __restrict__ x, const float* __restrict__ sw,
                        const float* __restrict__ sb, float* __restrict__ out) {
    const int lane = threadIdx.x;   // 64
    float s = 0.f;
#pragma unroll
    for (int t = 0; t < 8; ++t) {
        int k = lane + 64 * t;
        s += x[k] * sw[k];
    }
#pragma unroll
    for (int off = 32; off; off >>= 1) s += __shfl_xor(s, off, 64);
    if (lane == 0) out[0] = s + sb[0];
}

// ---------- launcher ----------
extern "C" void kernel_launch(void* const* d_in, const int* in_sizes, int n_in,
                              void* d_out, int out_size, void* d_ws, size_t ws_size,
                              hipStream_t stream) {
    (void)in_sizes; (void)n_in; (void)out_size; (void)ws_size;
    const float* attn_mem = (const float*)d_in[0];
    const float* attn_wm  = (const float*)d_in[1];
    const float* attn_wq  = (const float*)d_in[2];
    const float* attn_v   = (const float*)d_in[3];
    const float* hop_wm   = (const float*)d_in[4];
    const float* hop_wq   = (const float*)d_in[5];
    const float* hop_v    = (const float*)d_in[6];
    const float* init_i   = (const float*)d_in[7];
    const float* init_h   = (const float*)d_in[8];
    const float* init_c   = (const float*)d_in[9];
    const float* w_ih     = (const float*)d_in[10];
    const float* w_hh     = (const float*)d_in[11];
    const float* b_ih     = (const float*)d_in[12];
    const float* b_hh     = (const float*)d_in[13];
    const float* score_w  = (const float*)d_in[14];
    const float* score_b  = (const float*)d_in[15];
    const int*   mask     = (const int*)d_in[16];
    float* dout = (float*)d_out;

    size_t off = 0;
    char* base = (char*)d_ws;
    auto carve = [&](size_t bytes) -> char* {
        char* p = base + off;
        off += (bytes + 255) & ~(size_t)255;
        return p;
    };
    ushort_t* Abf  = (ushort_t*)carve((size_t)NN * DD * 2);
    ushort_t* WT0  = (ushort_t*)carve((size_t)DD * HH * 2);
    ushort_t* WT1  = (ushort_t*)carve((size_t)DD * HH * 2);
    ushort_t* afeat = (ushort_t*)carve((size_t)NN * HH * 2);
    ushort_t* hfeat = (ushort_t*)carve((size_t)NN * HH * 2);
    float* pacc  = (float*)carve((size_t)NWAVE * HH * 4);
    float* pl    = (float*)carve((size_t)NWAVE * 4);
    float* gates = (float*)carve(4 * HH * 4);
    float* hbuf  = (float*)carve(HH * 4);
    float* cb0   = (float*)carve(HH * 4);
    float* cb1   = (float*)carve(HH * 4);
    float* qbuf  = (float*)carve(HH * 4);
    float* qwbuf = (float*)carve(HH * 4);
    float* xbuf  = (float*)carve(DD * 4);

    conv_bf16<<<(NN * DD / 8) / 256, 256, 0, stream>>>(attn_mem, Abf);
    conv_wt<<<dim3(128, 2), 256, 0, stream>>>(attn_wm, hop_wm, WT0, WT1);
    gemm_mfma<<<4096, 256, 0, stream>>>(Abf, WT0, WT1,
        (__hip_bfloat16*)afeat, (__hip_bfloat16*)hfeat);

    for (int s = 0; s < NSTEP; ++s) {
        const float* x   = s ? xbuf : init_i;
        const float* hin = s ? hbuf : init_h;
        const float* cin = s == 0 ? init_c : (s & 1 ? cb0 : cb1);
        float* cout      = (s & 1) ? cb1 : cb0;
        lstm_gates<<<512, 256, 0, stream>>>(x, hin, w_ih, w_hh, b_ih, b_hh, gates);
        lstm_tail<<<8, 512, 0, stream>>>(gates, cin, cout, hbuf, hop_wq, qwbuf);
        attn_partial<true><<<ABLOCKS, 256, 0, stream>>>(hfeat, nullptr, qwbuf, hop_v, mask, pl, pacc);
        attn_combine<<<64, 256, 0, stream>>>(pl, pacc, qbuf);
        vecmat512<<<8, 512, 0, stream>>>(qbuf, attn_wq, qwbuf);
        attn_partial<false><<<ABLOCKS, 256, 0, stream>>>(afeat, Abf, qwbuf, attn_v, mask, pl, pacc);
        attn_combine<<<64, 256, 0, stream>>>(pl, pacc, xbuf);
        score_k<<<1, 64, 0, stream>>>(xbuf, score_w, score_b, dout + s);
    }
}

// Round 13
// 337.146 us; speedup vs baseline: 1.7849x; 1.4881x over previous
//
#include <hip/hip_runtime.h>
#include <hip/hip_bf16.h>

#define NN 65536
#define DD 512
#define HH 512
#define NSTEP 4
#define NEG_INFF -100000000.0f

#define RPW 16                 // rows per wave in attn_partial
#define ABLOCKS 1024
#define NWAVE (ABLOCKS * 4)    // worst-case waves (all rows unmasked)

typedef unsigned short ushort_t;
typedef __attribute__((ext_vector_type(8))) short bf16x8;
typedef __attribute__((ext_vector_type(4))) float f32x4;

// ---------- helpers ----------
__device__ __forceinline__ float bflo(unsigned u) {
    union { unsigned i; float f; } v; v.i = u << 16; return v.f;
}
__device__ __forceinline__ float bfhi(unsigned u) {
    union { unsigned i; float f; } v; v.i = u & 0xffff0000u; return v.f;
}
__device__ __forceinline__ float fast_tanh(float x) {
    float e = __expf(2.0f * x);
    return 1.0f - 2.0f * __builtin_amdgcn_rcpf(e + 1.0f);
}

#define GL2LDS(g, l) __builtin_amdgcn_global_load_lds( \
    (const __attribute__((address_space(1))) unsigned int*)(g), \
    (__attribute__((address_space(3))) unsigned int*)(l), 16, 0, 0)

// ---------- mask compaction: count per 256-chunk ----------
__global__ __launch_bounds__(256)
void mask_count(const int* __restrict__ mask, int* __restrict__ bcount) {
    __shared__ int red[4];
    const int t = threadIdx.x;
    int v = mask[blockIdx.x * 256 + t] ? 1 : 0;
#pragma unroll
    for (int o = 32; o; o >>= 1) v += __shfl_xor(v, o, 64);
    if ((t & 63) == 0) red[t >> 6] = v;
    __syncthreads();
    if (t == 0) bcount[blockIdx.x] = red[0] + red[1] + red[2] + red[3];
}

// ---------- mask compaction: order-preserving index write + total ----------
__global__ __launch_bounds__(256)
void mask_compact(const int* __restrict__ mask, const int* __restrict__ bcount,
                  int* __restrict__ cidx, int* __restrict__ Mc) {
    __shared__ int scan[256];
    __shared__ int base_s;
    const int t = threadIdx.x, b = blockIdx.x;
    if (t == 0) {
        int base = 0;
        for (int i = 0; i < b; ++i) base += bcount[i];
        base_s = base;
        if (b == 0) {
            int tot = 0;
            for (int i = 0; i < 256; ++i) tot += bcount[i];
            Mc[0] = tot;
        }
    }
    const int m = mask[b * 256 + t] ? 1 : 0;
    scan[t] = m;
    __syncthreads();
    for (int o = 1; o < 256; o <<= 1) {
        const int val = (t >= o) ? scan[t - o] : 0;
        __syncthreads();
        scan[t] += val;
        __syncthreads();
    }
    if (m) cidx[base_s + scan[t] - 1] = b * 256 + t;
}

// ---------- gather + f32->bf16: Abf_c[r] = bf16(attn_mem[cidx[r]]); zero-pad ----------
// grid 16384 x 256: block = 4 rows, 64 threads/row x 8 elems
__global__ __launch_bounds__(256)
void gather_bf16(const float* __restrict__ in, const int* __restrict__ cidx,
                 const int* __restrict__ Mc, ushort_t* __restrict__ out) {
    const int r = blockIdx.x * 4 + (threadIdx.x >> 6);
    const int mc = Mc[0];
    const int pad = (mc + 127) & ~127;
    if (r >= pad) return;
    const int e0 = (threadIdx.x & 63) * 8;
    union { __hip_bfloat16 h[8]; uint4 u; } t;
    if (r < mc) {
        const float* src = in + (size_t)cidx[r] * DD + e0;
        float4 a = *(const float4*)src;
        float4 b = *(const float4*)(src + 4);
        t.h[0] = __float2bfloat16(a.x); t.h[1] = __float2bfloat16(a.y);
        t.h[2] = __float2bfloat16(a.z); t.h[3] = __float2bfloat16(a.w);
        t.h[4] = __float2bfloat16(b.x); t.h[5] = __float2bfloat16(b.y);
        t.h[6] = __float2bfloat16(b.z); t.h[7] = __float2bfloat16(b.w);
    } else {
        t.u = make_uint4(0, 0, 0, 0);
    }
    *(uint4*)&out[(size_t)r * DD + e0] = t.u;
}

// ---------- weight transpose + convert: WT[n][k] = bf16(W[k][n]) ----------
__global__ __launch_bounds__(256)
void conv_wt(const float* __restrict__ W0, const float* __restrict__ W1,
             ushort_t* __restrict__ T0, ushort_t* __restrict__ T1) {
    const float* W = blockIdx.y ? W1 : W0;
    ushort_t* T = blockIdx.y ? T1 : T0;
    const int n = blockIdx.x * 4 + (threadIdx.x >> 6);
    const int k0 = (threadIdx.x & 63) * 8;
    union { __hip_bfloat16 h[8]; uint4 u; } t;
#pragma unroll
    for (int i = 0; i < 8; ++i)
        t.h[i] = __float2bfloat16(W[(size_t)(k0 + i) * HH + n]);
    *(uint4*)&T[(size_t)n * DD + k0] = t.u;
}

// ---------- MFMA GEMM on compacted rows (dynamic M), XCD round-robin ----------
#define TM 128
#define TK 32
#define NT (DD / TK)   // 16 K-steps
__global__ __launch_bounds__(256)
void gemm_mfma(const ushort_t* __restrict__ A, const int* __restrict__ Mc,
               const ushort_t* __restrict__ WT0, const ushort_t* __restrict__ WT1,
               __hip_bfloat16* __restrict__ C0, __hip_bfloat16* __restrict__ C1) {
    __shared__ char smem[32768];
    ushort_t* AsB = (ushort_t*)smem;            // [2][4096]
    ushort_t* BsB = (ushort_t*)(smem + 16384);
    const int L = blockIdx.x;
    const int xcd = L & 7;
    const int slot = L >> 3;
    const int mt = (slot >> 3) * 8 + xcd;       // round-robin M-tiles across XCDs
    const int ntile = (Mc[0] + 127) >> 7;
    if (mt >= ntile) return;
    const int my = slot & 7;
    const ushort_t* WT = (my < 4) ? WT0 : WT1;
    __hip_bfloat16* Cp = (my < 4) ? C0 : C1;
    const int bn = (my & 3) * TM;
    const int bm = mt * TM;
    const int tid = threadIdx.x;
    const int lane = tid & 63;
    const int wid = tid >> 6;
    const int wr = (wid >> 1) * 64;
    const int wc = (wid & 1) * 64;
    const int l15 = lane & 15;
    const int srow = lane >> 2;
    const int ske = (((lane & 3) ^ ((lane >> 3) & 3)) * 8);
    const int koff = (((lane >> 4) ^ ((l15 >> 1) & 3)) << 3);

    const ushort_t* Abase = A + (size_t)bm * DD;
    const ushort_t* Bbase = WT + (size_t)bn * DD;

    auto stage = [&](int b, int k0) {
#pragma unroll
        for (int u = 0; u < 2; ++u) {
            const int g = u * 4 + wid;
            const int row = g * 16 + srow;
            GL2LDS(Abase + (size_t)row * DD + k0 + ske, AsB + b * 4096 + g * 512);
            GL2LDS(Bbase + (size_t)row * DD + k0 + ske, BsB + b * 4096 + g * 512);
        }
    };

    const f32x4 zero = {0.f, 0.f, 0.f, 0.f};
    f32x4 acc[4][4];
#pragma unroll
    for (int m = 0; m < 4; ++m)
#pragma unroll
        for (int n = 0; n < 4; ++n) acc[m][n] = zero;

    stage(0, 0);
    stage(1, TK);
    __builtin_amdgcn_sched_barrier(0);

    for (int t = 0; t < NT; ++t) {
        const int cur = t & 1;
        if (t + 1 < NT) asm volatile("s_waitcnt vmcnt(4)" ::: "memory");
        else            asm volatile("s_waitcnt vmcnt(0)" ::: "memory");
        __builtin_amdgcn_sched_barrier(0);
        __builtin_amdgcn_s_barrier();
        __builtin_amdgcn_sched_barrier(0);

        bf16x8 af[4], bfr[4];
#pragma unroll
        for (int m = 0; m < 4; ++m)
            af[m] = *(const bf16x8*)(AsB + cur * 4096 + (wr + m * 16 + l15) * TK + koff);
#pragma unroll
        for (int n = 0; n < 4; ++n)
            bfr[n] = *(const bf16x8*)(BsB + cur * 4096 + (wc + n * 16 + l15) * TK + koff);
#pragma unroll
        for (int m = 0; m < 4; ++m)
#pragma unroll
            for (int n = 0; n < 4; ++n)
                acc[m][n] = __builtin_amdgcn_mfma_f32_16x16x32_bf16(af[m], bfr[n], acc[m][n], 0, 0, 0);

        asm volatile("s_waitcnt lgkmcnt(0)" ::: "memory");
        __builtin_amdgcn_sched_barrier(0);
        __builtin_amdgcn_s_barrier();
        __builtin_amdgcn_sched_barrier(0);
        if (t + 2 < NT) stage(cur, (t + 2) * TK);
        __builtin_amdgcn_sched_barrier(0);
    }

    // LDS-transposed epilogue, 16B coalesced stores
    float* Cs = (float*)smem + wid * (16 * 68);
    const int r0w = (lane >> 4) * 4;
    const int lr = lane >> 2;
    const int lc = (lane & 3) * 16;
#pragma unroll
    for (int m = 0; m < 4; ++m) {
#pragma unroll
        for (int n = 0; n < 4; ++n) {
            const f32x4 vvv = acc[m][n];
#pragma unroll
            for (int r = 0; r < 4; ++r)
                Cs[(r0w + r) * 68 + n * 16 + l15] = vvv[r];
        }
        asm volatile("s_waitcnt lgkmcnt(0)" ::: "memory");
        __builtin_amdgcn_s_barrier();
        union { __hip_bfloat16 h[16]; uint4 u[2]; } pk;
#pragma unroll
        for (int j = 0; j < 16; ++j)
            pk.h[j] = __float2bfloat16(Cs[lr * 68 + lc + j]);
        const size_t rb = (size_t)(bm + wr + m * 16 + lr) * HH + bn + wc + lc;
        *(uint4*)&Cp[rb]     = pk.u[0];
        *(uint4*)&Cp[rb + 8] = pk.u[1];
        asm volatile("s_waitcnt lgkmcnt(0)" ::: "memory");
        __builtin_amdgcn_s_barrier();
    }
}

// ---------- LSTM gates ----------
__global__ __launch_bounds__(256)
void lstm_gates(const float* __restrict__ x, const float* __restrict__ h,
                const float* __restrict__ w_ih, const float* __restrict__ w_hh,
                const float* __restrict__ b_ih, const float* __restrict__ b_hh,
                float* __restrict__ gates) {
    const int wave = (blockIdx.x * 256 + threadIdx.x) >> 6;
    const int lane = threadIdx.x & 63;
    const float* wi = w_ih + (size_t)wave * DD;
    const float* wh = w_hh + (size_t)wave * HH;
    float s = 0.f;
#pragma unroll
    for (int t = 0; t < 8; ++t) {
        int k = lane + 64 * t;
        s += wi[k] * x[k] + wh[k] * h[k];
    }
#pragma unroll
    for (int off = 32; off; off >>= 1) s += __shfl_xor(s, off, 64);
    if (lane == 0) gates[wave] = s + b_ih[wave] + b_hh[wave];
}

// ---------- fused LSTM h/c + qw = h @ hop_wq ----------
__global__ __launch_bounds__(512)
void lstm_tail(const float* __restrict__ gates, const float* __restrict__ cin,
               float* __restrict__ cout, float* __restrict__ hout,
               const float* __restrict__ Wq, float* __restrict__ qwout) {
    __shared__ float hs[HH];
    __shared__ float red[8][64];
    const int j = threadIdx.x;
    {
        float ig = gates[j], fg = gates[HH + j], gg = gates[2 * HH + j], og = gates[3 * HH + j];
        float si = 1.f / (1.f + __expf(-ig));
        float sf = 1.f / (1.f + __expf(-fg));
        float so = 1.f / (1.f + __expf(-og));
        float cn = sf * cin[j] + si * tanhf(gg);
        float hn = so * tanhf(cn);
        hs[j] = hn;
        if (blockIdx.x == 0) { cout[j] = cn; hout[j] = hn; }
    }
    __syncthreads();
    const int lane = threadIdx.x & 63, wv = threadIdx.x >> 6;
    const int col = blockIdx.x * 64 + lane;
    float s = 0.f;
    const int k0 = wv * 64;
#pragma unroll 4
    for (int k = k0; k < k0 + 64; ++k) s += hs[k] * Wq[(size_t)k * HH + col];
    red[wv][lane] = s;
    __syncthreads();
    if (wv == 0) {
        float t = 0.f;
#pragma unroll
        for (int r = 0; r < 8; ++r) t += red[r][lane];
        qwout[col] = t;
    }
}

// ---------- qw = q @ W (512x512), grid 8 x 512 ----------
__global__ __launch_bounds__(512)
void vecmat512(const float* __restrict__ q, const float* __restrict__ W,
               float* __restrict__ out) {
    __shared__ float red[8][64];
    const int lane = threadIdx.x & 63, wv = threadIdx.x >> 6;
    const int j = blockIdx.x * 64 + lane;
    float s = 0.f;
    const int k0 = wv * 64;
#pragma unroll 4
    for (int k = k0; k < k0 + 64; ++k) s += q[k] * W[(size_t)k * HH + j];
    red[wv][lane] = s;
    __syncthreads();
    if (wv == 0) {
        float t = 0.f;
#pragma unroll
        for (int r = 0; r < 8; ++r) t += red[r][lane];
        out[j] = t;
    }
}

// ---------- attention phase A on compacted rows (r6-proven body) ----------
// All compact rows are unmasked; rows >= Mc (pad) get weight exp(-1e8)==0.
template<bool HOP>
__global__ __launch_bounds__(256)
void attn_partial(const ushort_t* __restrict__ feat,
                  const ushort_t* __restrict__ mem,
                  const float* __restrict__ qw,
                  const float* __restrict__ v,
                  const int* __restrict__ Mc,
                  float* __restrict__ pl, float* __restrict__ pacc) {
    const int gtid = blockIdx.x * 256 + threadIdx.x;
    const int wave = gtid >> 6;
    const int mc = Mc[0];
    const int nwc = (mc + RPW - 1) / RPW;
    if (wave >= nwc) return;
    const int lane = threadIdx.x & 63;
    float qv[8], vv[8];
    {
        float4 q0 = *(const float4*)&qw[lane * 8];
        float4 q1 = *(const float4*)&qw[lane * 8 + 4];
        qv[0] = q0.x; qv[1] = q0.y; qv[2] = q0.z; qv[3] = q0.w;
        qv[4] = q1.x; qv[5] = q1.y; qv[6] = q1.z; qv[7] = q1.w;
        float4 v0 = *(const float4*)&v[lane * 8];
        float4 v1 = *(const float4*)&v[lane * 8 + 4];
        vv[0] = v0.x; vv[1] = v0.y; vv[2] = v0.z; vv[3] = v0.w;
        vv[4] = v1.x; vv[5] = v1.y; vv[6] = v1.z; vv[7] = v1.w;
    }
    float C = 0.f;
#pragma unroll
    for (int j = 0; j < 8; ++j) C += fabsf(vv[j]);
#pragma unroll
    for (int off = 32; off; off >>= 1) C += __shfl_xor(C, off, 64);

    float lsum = 0.f;
    float acc[8];
#pragma unroll
    for (int j = 0; j < 8; ++j) acc[j] = 0.f;
    const int row0 = wave * RPW;

    uint4 fc = *(const uint4*)(feat + (size_t)row0 * HH + lane * 8);
    uint4 mc4;
    if (!HOP) mc4 = *(const uint4*)(mem + (size_t)row0 * DD + lane * 8);
#pragma unroll 4
    for (int r = 0; r < RPW; ++r) {
        uint4 fn, mn;
        if (r + 1 < RPW) {
            fn = *(const uint4*)(feat + (size_t)(row0 + r + 1) * HH + lane * 8);
            if (!HOP) mn = *(const uint4*)(mem + (size_t)(row0 + r + 1) * DD + lane * 8);
        }
        float f[8];
        f[0] = bflo(fc.x); f[1] = bfhi(fc.x); f[2] = bflo(fc.y); f[3] = bfhi(fc.y);
        f[4] = bflo(fc.z); f[5] = bfhi(fc.z); f[6] = bflo(fc.w); f[7] = bfhi(fc.w);
        float mv[8];
        if (!HOP) {
            mv[0] = bflo(mc4.x); mv[1] = bfhi(mc4.x); mv[2] = bflo(mc4.y); mv[3] = bfhi(mc4.y);
            mv[4] = bflo(mc4.z); mv[5] = bfhi(mc4.z); mv[6] = bflo(mc4.w); mv[7] = bfhi(mc4.w);
        } else {
#pragma unroll
            for (int j = 0; j < 8; ++j) mv[j] = f[j];
        }
        float d = 0.f;
#pragma unroll
        for (int j = 0; j < 8; ++j) d += fast_tanh(f[j] + qv[j]) * vv[j];
#pragma unroll
        for (int off = 32; off; off >>= 1) d += __shfl_xor(d, off, 64);
        const float sc = d - C + ((row0 + r < mc) ? 0.f : NEG_INFF);
        const float p = __expf(sc);
        lsum += p;
#pragma unroll
        for (int j = 0; j < 8; ++j) acc[j] += p * mv[j];
        fc = fn;
        if (!HOP) mc4 = mn;
    }
    const size_t base = (size_t)wave * HH + lane * 8;
    *(float4*)&pacc[base]     = make_float4(acc[0], acc[1], acc[2], acc[3]);
    *(float4*)&pacc[base + 4] = make_float4(acc[4], acc[5], acc[6], acc[7]);
    if (lane == 0) pl[wave] = lsum;
}

// ---------- attention phase B: sum of active partials; grid 64 x 256 ----------
__global__ __launch_bounds__(256)
void attn_combine(const float* __restrict__ pl, const float* __restrict__ pacc,
                  const int* __restrict__ Mc, float* __restrict__ out) {
    __shared__ float red[256];
    const int tid = threadIdx.x;
    const int lane = tid & 63, wv = tid >> 6;
    const int nwc = (Mc[0] + RPW - 1) / RPW;
    float lg = 0.f;
    for (int b = tid; b < nwc; b += 256) lg += pl[b];
#pragma unroll
    for (int off = 32; off; off >>= 1) lg += __shfl_xor(lg, off, 64);
    if (lane == 0) red[wv] = lg;
    __syncthreads();
    lg = red[0] + red[1] + red[2] + red[3];
    const float inv = 1.0f / lg;
    __syncthreads();
    const int c0 = blockIdx.x * 8;
    float a[8];
#pragma unroll
    for (int j = 0; j < 8; ++j) a[j] = 0.f;
    for (int b = tid; b < nwc; b += 256) {
        float4 p0 = *(const float4*)&pacc[(size_t)b * HH + c0];
        float4 p1 = *(const float4*)&pacc[(size_t)b * HH + c0 + 4];
        a[0] += p0.x; a[1] += p0.y; a[2] += p0.z; a[3] += p0.w;
        a[4] += p1.x; a[5] += p1.y; a[6] += p1.z; a[7] += p1.w;
    }
#pragma unroll
    for (int j = 0; j < 8; ++j)
#pragma unroll
        for (int off = 32; off; off >>= 1) a[j] += __shfl_xor(a[j], off, 64);
    if (lane == 0) {
#pragma unroll
        for (int j = 0; j < 8; ++j) red[wv * 8 + j] = a[j];
    }
    __syncthreads();
    if (tid < 8) {
        float s = red[tid] + red[8 + tid] + red[16 + tid] + red[24 + tid];
        out[c0 + tid] = s * inv;
    }
}

// ---------- score ----------
__global__ void score_k(const float* __restrict__ x, const float* __restrict__ sw,
                        const float* __restrict__ sb, float* __restrict__ out) {
    const int lane = threadIdx.x;   // 64
    float s = 0.f;
#pragma unroll
    for (int t = 0; t < 8; ++t) {
        int k = lane + 64 * t;
        s += x[k] * sw[k];
    }
#pragma unroll
    for (int off = 32; off; off >>= 1) s += __shfl_xor(s, off, 64);
    if (lane == 0) out[0] = s + sb[0];
}

// ---------- launcher ----------
extern "C" void kernel_launch(void* const* d_in, const int* in_sizes, int n_in,
                              void* d_out, int out_size, void* d_ws, size_t ws_size,
                              hipStream_t stream) {
    (void)in_sizes; (void)n_in; (void)out_size; (void)ws_size;
    const float* attn_mem = (const float*)d_in[0];
    const float* attn_wm  = (const float*)d_in[1];
    const float* attn_wq  = (const float*)d_in[2];
    const float* attn_v   = (const float*)d_in[3];
    const float* hop_wm   = (const float*)d_in[4];
    const float* hop_wq   = (const float*)d_in[5];
    const float* hop_v    = (const float*)d_in[6];
    const float* init_i   = (const float*)d_in[7];
    const float* init_h   = (const float*)d_in[8];
    const float* init_c   = (const float*)d_in[9];
    const float* w_ih     = (const float*)d_in[10];
    const float* w_hh     = (const float*)d_in[11];
    const float* b_ih     = (const float*)d_in[12];
    const float* b_hh     = (const float*)d_in[13];
    const float* score_w  = (const float*)d_in[14];
    const float* score_b  = (const float*)d_in[15];
    const int*   mask     = (const int*)d_in[16];
    float* dout = (float*)d_out;

    size_t off = 0;
    char* base = (char*)d_ws;
    auto carve = [&](size_t bytes) -> char* {
        char* p = base + off;
        off += (bytes + 255) & ~(size_t)255;
        return p;
    };
    ushort_t* Abf   = (ushort_t*)carve((size_t)NN * DD * 2);   // compacted
    ushort_t* WT0   = (ushort_t*)carve((size_t)DD * HH * 2);
    ushort_t* WT1   = (ushort_t*)carve((size_t)DD * HH * 2);
    ushort_t* afeat = (ushort_t*)carve((size_t)NN * HH * 2);   // compacted
    ushort_t* hfeat = (ushort_t*)carve((size_t)NN * HH * 2);   // compacted
    float* pacc  = (float*)carve((size_t)NWAVE * HH * 4);
    float* pl    = (float*)carve((size_t)NWAVE * 4);
    int* bcount  = (int*)carve(256 * 4);
    int* cidx    = (int*)carve((size_t)NN * 4);
    int* Mc      = (int*)carve(256);
    float* gates = (float*)carve(4 * HH * 4);
    float* hbuf  = (float*)carve(HH * 4);
    float* cb0   = (float*)carve(HH * 4);
    float* cb1   = (float*)carve(HH * 4);
    float* qbuf  = (float*)carve(HH * 4);
    float* qwbuf = (float*)carve(HH * 4);
    float* xbuf  = (float*)carve(DD * 4);

    mask_count<<<256, 256, 0, stream>>>(mask, bcount);
    mask_compact<<<256, 256, 0, stream>>>(mask, bcount, cidx, Mc);
    gather_bf16<<<NN / 4, 256, 0, stream>>>(attn_mem, cidx, Mc, Abf);
    conv_wt<<<dim3(128, 2), 256, 0, stream>>>(attn_wm, hop_wm, WT0, WT1);
    gemm_mfma<<<4096, 256, 0, stream>>>(Abf, Mc, WT0, WT1,
        (__hip_bfloat16*)afeat, (__hip_bfloat16*)hfeat);

    for (int s = 0; s < NSTEP; ++s) {
        const float* x   = s ? xbuf : init_i;
        const float* hin = s ? hbuf : init_h;
        const float* cin = s == 0 ? init_c : (s & 1 ? cb0 : cb1);
        float* cout      = (s & 1) ? cb1 : cb0;
        lstm_gates<<<512, 256, 0, stream>>>(x, hin, w_ih, w_hh, b_ih, b_hh, gates);
        lstm_tail<<<8, 512, 0, stream>>>(gates, cin, cout, hbuf, hop_wq, qwbuf);
        attn_partial<true><<<ABLOCKS, 256, 0, stream>>>(hfeat, nullptr, qwbuf, hop_v, Mc, pl, pacc);
        attn_combine<<<64, 256, 0, stream>>>(pl, pacc, Mc, qbuf);
        vecmat512<<<8, 512, 0, stream>>>(qbuf, attn_wq, qwbuf);
        attn_partial<false><<<ABLOCKS, 256, 0, stream>>>(afeat, Abf, qwbuf, attn_v, Mc, pl, pacc);
        attn_combine<<<64, 256, 0, stream>>>(pl, pacc, Mc, xbuf);
        score_k<<<1, 64, 0, stream>>>(xbuf, score_w, score_b, dout + s);
    }
}